// Round 2
// baseline (404.850 us; speedup 1.0000x reference)
//
#include <hip/hip_runtime.h>

// out[b,c,y,x] = sum_{dy,dx in [0,13)} aff[b, dy*13+dx, y, x] * in2_zp[b, c, y+dy-6, x+dx-6]
// B=4 C=64 H=W=192 D=169.
//
// Round 8: kill the load->pack->use serialization that flatlined rounds 6/7.
// Round 7 post-mortem: VGPR=104 << 185-reg working set => compiler sank the
// 13 aff loads into aff_pack, paying ~900cy HBM latency per few-load chunk,
// twice per iteration (VALUBusy 23%, dur unchanged at 190us, HBM 10%).
// Fix is structural, not scheduling hints on the old shape:
//  * aff stays fp32 in regs and feeds v_fma_mix_f32 directly
//    (fmaf(f32, (float)_Float16, f32) folds to mix w/ op_sel) -> the pack
//    stage and the shift ops are GONE; nothing consumes aff except the pass.
//  * window stays fp16 in LDS (pitch 42 words, proven layout; b64 reads are
//    at the structural 4-way minimum).
//  * TY=1: live set = Af 52 + acc 16 + Sv 20 + misc ~= 120 regs -> fits the
//    128-reg / 4-waves-per-SIMD budget; amdgpu_waves_per_eu(3,4).
//  * sched_barrier(0) after the load-issue block: all 18 global loads issue
//    before the pass; the pass's fma stream + 3 other resident blocks/CU
//    (LDS 21KB, one wave/SIMD per block => desynced stalls) cover latency.
//  * 1-D grid, y-fastest within an XCD: 12/13 staged in2 rows L2-hot.
// Numerics: aff fp32 (better than r7), in2 fp16 rtz, fp32 accum.

#define KD   6
#define WIN  13
#define ND   169
#define NB   4
#define NC   64
#define NH   192
#define NW   192
#define XH   64            // x-tile width per block (3 tiles across W)
#define PITCHW 42          // LDS row pitch in 32-bit words (84 halves >= 80)
#define BUFW (NC * PITCHW) // 2688 words per buffer
#define NTH  256           // 4 waves

typedef _Float16 half2v __attribute__((ext_vector_type(2)));

static __device__ __forceinline__ half2v h2(unsigned u) {
    return __builtin_bit_cast(half2v, u);
}
static __device__ __forceinline__ unsigned pk(float a, float b) {
    return __builtin_bit_cast(unsigned, __builtin_amdgcn_cvt_pkrtz(a, b));
}
// half 'sel' of word w, as float (v_fma_mix folds the fpext into op_sel).
static __device__ __forceinline__ float hget(unsigned w, int sel) {
    const half2v h = h2(w);
    return sel ? (float)h.y : (float)h.x;
}

__global__ __launch_bounds__(NTH)
__attribute__((amdgpu_waves_per_eu(3, 4)))
void mxassemble(const float* __restrict__ aff,
                const float* __restrict__ in2,
                float* __restrict__ out) {
    __shared__ unsigned ldsw[2 * BUFW];   // 21504 B; word = 2 fp16 halves

    // 1-D grid, XCD-partitioned: bx = (m<<3)|g. Per XCD g: m in [0,288) =
    // b(4) x xb(3) x yl(24), yl fastest -> neighbor blocks share 12 rows.
    const int bx  = blockIdx.x;
    const int g   = bx & 7;
    const int m   = bx >> 3;               // 0..287
    const int b   = m / 72;
    const int r72 = m - 72 * b;
    const int xb  = r72 / 24;
    const int yl  = r72 - 24 * xb;
    const int y   = 24 * g + yl;
    const int X0  = xb * XH;

    const int t    = threadIdx.x;
    const int l    = t & 63;
    const int wv   = t >> 6;               // wave 0..3
    const int cg   = l & 15;               // channel group; c = cg + 16*i
    const int xs   = l >> 4;               // 0..3
    const int slot = wv * 4 + xs;          // 0..15
    const int x0   = X0 + slot * 4;

    // Row layout: half j in [0,80) <-> global x = X0 - 8 + j.
    // Zero the 8-half OOB aprons once (xb=0: words 0..3; xb=2: words 36..39).
    if (xb != 1) {
        const int w0 = (xb == 0) ? 0 : 36;
        if (t < NC * 2) {
            const int c = t >> 1, qq = t & 1;
            *(uint2*)&ldsw[c * PITCHW + w0 + 2 * qq]        = make_uint2(0u, 0u);
            *(uint2*)&ldsw[BUFW + c * PITCHW + w0 + 2 * qq] = make_uint2(0u, 0u);
        }
    }

    // Staging slots: item s covers (c, q) = 4 floats; 64ch x 20 chunks =
    // 1280 = 256 threads x 5.
    int wadr[5], goff[5];
#pragma unroll
    for (int s = 0; s < 5; ++s) {
        const int ii = t + NTH * s;
        const int c  = ii / 20;
        const int q  = ii - 20 * c;
        const int xg = X0 - 8 + 4 * q;
        const bool ok = (xg >= 0) && (xg < NW);
        wadr[s] = ok ? (c * PITCHW + 2 * q) : -1;
        goff[s] = c * (NH * NW) + xg;
    }

    float acc[4][4];
#pragma unroll
    for (int i = 0; i < 4; ++i)
#pragma unroll
        for (int j = 0; j < 4; ++j) acc[i][j] = 0.f;

    const float* in2_b = in2 + (size_t)b * NC * NH * NW;
    const float* apc   = aff + (size_t)b * ND * NH * NW + (size_t)y * NW + x0;
    const int wbase = cg * PITCHW + 2 * slot;

    // ---- prologue: stage row y-6 into buf0 ----
    {
        const int r0 = y - KD;
        if (r0 >= 0) {
            const float* p = in2_b + (size_t)r0 * NW;
            float4 Sv[5];
#pragma unroll
            for (int s = 0; s < 5; ++s)
                if (wadr[s] >= 0) Sv[s] = *(const float4*)&p[goff[s]];
#pragma unroll
            for (int s = 0; s < 5; ++s)
                if (wadr[s] >= 0) {
                    uint2 w; w.x = pk(Sv[s].x, Sv[s].y); w.y = pk(Sv[s].z, Sv[s].w);
                    *(uint2*)&ldsw[wadr[s]] = w;
                }
        }
    }
    __syncthreads();

    for (int rr = 0; rr < WIN; ++rr) {
        const unsigned* cur = ldsw + ((rr & 1) ? BUFW : 0);
        unsigned*       nxt = ldsw + ((rr & 1) ? 0 : BUFW);
        const int  r  = y - KD + rr;
        const bool pv = (r >= 0) && (r < NH);          // block-uniform
        const int  rn = r + 1;
        const bool sv = (rr < WIN - 1) && (rn >= 0) && (rn < NH);

        // 1. issue the 13 aff float4 loads (dy = rr), fp32, straight to regs
        alignas(16) float Afr[WIN][4];
        if (pv) {
#pragma unroll
            for (int dx = 0; dx < WIN; ++dx)
                *(float4*)&Afr[dx][0] =
                    *(const float4*)&apc[(size_t)dx * (NH * NW)];
        }
        // 2. issue in2 staging loads for row rn
        float4 Sv[5];
        if (sv) {
            const float* p = in2_b + (size_t)rn * NW;
#pragma unroll
            for (int s = 0; s < 5; ++s)
                if (wadr[s] >= 0) Sv[s] = *(const float4*)&p[goff[s]];
        }
        // Pin: all 18 global loads are issued before anything below.
        __builtin_amdgcn_sched_barrier(0);

        // 3. pass: 4 channels x 4 x's x 13 taps of v_fma_mix
        if (pv) {
            const unsigned* wb = cur + wbase;
#pragma unroll
            for (int i = 0; i < 4; ++i) {              // c = cg + 16*i
                const unsigned* wp = wb + i * (16 * PITCHW);
                unsigned W[10];
                *(uint2*)&W[0] = *(const uint2*)&wp[0];
                *(uint2*)&W[2] = *(const uint2*)&wp[2];
                *(uint2*)&W[4] = *(const uint2*)&wp[4];
                *(uint2*)&W[6] = *(const uint2*)&wp[6];
                *(uint2*)&W[8] = *(const uint2*)&wp[8];
#pragma unroll
                for (int j = 0; j < 4; ++j) {
                    float a = acc[i][j];
#pragma unroll
                    for (int dx = 0; dx < WIN; ++dx) {
                        const int mm = j + dx + 2;     // half index in window
                        a = fmaf(Afr[dx][j], hget(W[mm >> 1], mm & 1), a);
                    }
                    acc[i][j] = a;
                }
            }
        }

        // 4. pack + write the staged row into the other buffer
        if (sv) {
#pragma unroll
            for (int s = 0; s < 5; ++s)
                if (wadr[s] >= 0) {
                    uint2 w; w.x = pk(Sv[s].x, Sv[s].y); w.y = pk(Sv[s].z, Sv[s].w);
                    *(uint2*)&nxt[wadr[s]] = w;
                }
        }

        apc += (size_t)WIN * NH * NW;
        __syncthreads();   // one barrier per row-iteration (double buffer)
    }

    float* ob = out + (((size_t)b * NC + cg) * NH + y) * NW + x0;
#pragma unroll
    for (int i = 0; i < 4; ++i) {
        *(float4*)&ob[(size_t)(16 * i) * NH * NW] =
            make_float4(acc[i][0], acc[i][1], acc[i][2], acc[i][3]);
    }
}

extern "C" void kernel_launch(void* const* d_in, const int* in_sizes, int n_in,
                              void* d_out, int out_size, void* d_ws, size_t ws_size,
                              hipStream_t stream) {
    const float* aff = (const float*)d_in[0];   // [4,169,192,192] f32
    const float* in2 = (const float*)d_in[1];   // [4, 64,192,192] f32
    float* outp = (float*)d_out;                // [4, 64,192,192] f32
    dim3 grid(NB * NH * 3, 1, 1);               // 2304 blocks, 1-D XCD swizzle
    dim3 block(NTH);
    hipLaunchKernelGGL(mxassemble, grid, block, 0, stream, aff, in2, outp);
}

// Round 4
// 281.057 us; speedup vs baseline: 1.4405x; 1.4405x over previous
//
#include <hip/hip_runtime.h>

// out[b,c,y,x] = sum_{dy,dx in [0,13)} aff[b, dy*13+dx, y, x] * in2_zp[b, c, y+dy-6, x+dx-6]
// B=4 C=64 H=W=192 D=169.
//
// Round 10 = round 9 resubmitted: the r9 bench died in the harness
// ("MI355X container failed twice" — push-path flake; no dispatch ran, no
// counters). Static re-audit found no fault/hang path: uniform barriers,
// all LDS/global accesses in bounds, gll16 dest linear + 16B-aligned src,
// write-buffer never the read-buffer, live set ~110-125 VGPR < waves(3,4)
// cap. Design unchanged:
//  * aff global -> LDS via __builtin_amdgcn_global_load_lds (async, ZERO
//    VGPRs, cannot be sunk by regalloc — the failure mode that flatlined
//    r6/r7/r8: VGPR_Count 52/104/84 << working set, ~900cy HBM latency
//    exposed inside the pass every iteration).
//  * One gll16 call/iter stages the 13x64-float aff slice (lanes t<208:
//    dx = t>>4, x-chunk = t&15; LDS dest = wave base + lane*16, linear).
//  * Pass reads aff 4xfloat4 at a time via ds_read_b128 (fine-grained
//    lgkmcnt), v_fma_mix vs fp16 window from LDS. No pack stage exists.
//  * Working set by construction ~110 VGPR: W[4][10]=40 + affchunk 16 +
//    acc 16 + Sv 20 + addr. waves_per_eu(3,4) -> 4 waves/SIMD target; each
//    SIMD then hosts waves of DIFFERENT blocks (desynced barriers).
//  * Sv loads pinned with empty asm volatile so MachineSink can't move
//    them below the pass (r8's sched_barrier alone did not stop it).
//  * Grid (768,3), y-fastest within XCD (r7 measured WRITE=36.9MB ideal,
//    FETCH=115MB; r8's 1-D variant regressed both).
// Numerics: aff fp32 (exact), in2 fp16 rtz, fp32 accum. absmax <= 0.5.

#define KD   6
#define WIN  13
#define ND   169
#define NB   4
#define NC   64
#define NH   192
#define NW   192
#define XH   64            // x-tile width per block (3 tiles across W)
#define PITCHW 42          // window LDS row pitch in words (84 halves >= 80)
#define BUFW (NC * PITCHW) // 2688 words per window buffer
#define AFFW 832           // 13*64 words per aff slice buffer
#define NTH  256           // 4 waves

typedef _Float16 half2v __attribute__((ext_vector_type(2)));

static __device__ __forceinline__ half2v h2(unsigned u) {
    return __builtin_bit_cast(half2v, u);
}
static __device__ __forceinline__ unsigned pk(float a, float b) {
    return __builtin_bit_cast(unsigned, __builtin_amdgcn_cvt_pkrtz(a, b));
}
// half 'sel' of word w, as float (v_fma_mix folds the fpext into op_sel).
static __device__ __forceinline__ float hget(unsigned w, int sel) {
    const half2v h = h2(w);
    return sel ? (float)h.y : (float)h.x;
}
typedef const __attribute__((address_space(1))) void* gas_t;
typedef __attribute__((address_space(3))) void* sas_t;
static __device__ __forceinline__ void gll16(const float* g, unsigned* l) {
    __builtin_amdgcn_global_load_lds((gas_t)g, (sas_t)l, 16, 0, 0);
}

__global__ __launch_bounds__(NTH)
__attribute__((amdgpu_waves_per_eu(3, 4)))
void mxassemble(const float* __restrict__ aff,
                const float* __restrict__ in2,
                float* __restrict__ out) {
    __shared__ unsigned ldsw[2 * BUFW];   // fp16 window rows, double buffered
    __shared__ unsigned affw[2 * AFFW];   // fp32 aff slices, double buffered

    // Grid (768, 3): bx = (k<<3)|g. Per XCD g: k = b*24 + yl, yl fastest;
    // y = 24*g + yl -> each XCD owns a 24-row band per batch, rows L2-hot.
    const int bx = blockIdx.x;
    const int g  = bx & 7;
    const int k  = bx >> 3;                // 0..95
    const int b  = k / 24;
    const int yl = k - 24 * b;
    const int y  = 24 * g + yl;
    const int xb = blockIdx.y;             // x-tile 0..2
    const int X0 = xb * XH;

    const int t    = threadIdx.x;
    const int l    = t & 63;
    const int wv   = t >> 6;               // wave 0..3
    const int cg   = l & 15;               // channel group; c = cg + 16*i
    const int xs   = l >> 4;               // 0..3
    const int slot = wv * 4 + xs;          // 0..15
    const int x0   = X0 + slot * 4;

    // Window row layout: half j in [0,80) <-> global x = X0 - 8 + j.
    // Zero the 8-half OOB aprons once (xb=0: words 0..3; xb=2: words 36..39).
    if (xb != 1) {
        const int w0 = (xb == 0) ? 0 : 36;
        if (t < NC * 2) {
            const int c = t >> 1, qq = t & 1;
            *(uint2*)&ldsw[c * PITCHW + w0 + 2 * qq]        = make_uint2(0u, 0u);
            *(uint2*)&ldsw[BUFW + c * PITCHW + w0 + 2 * qq] = make_uint2(0u, 0u);
        }
    }

    // in2 staging slots: item s covers (c, q) = 4 floats; 64ch x 20 chunks
    // = 1280 = 256 threads x 5.
    int wadr[5], goff[5];
#pragma unroll
    for (int s = 0; s < 5; ++s) {
        const int ii = t + NTH * s;
        const int c  = ii / 20;
        const int q  = ii - 20 * c;
        const int xg = X0 - 8 + 4 * q;
        const bool ok = (xg >= 0) && (xg < NW);
        wadr[s] = ok ? (c * PITCHW + 2 * q) : -1;
        goff[s] = c * (NH * NW) + xg;
    }

    float acc[4][4];
#pragma unroll
    for (int i = 0; i < 4; ++i)
#pragma unroll
        for (int j = 0; j < 4; ++j) acc[i][j] = 0.f;

    const float* in2_b = in2 + (size_t)b * NC * NH * NW;
    const int wbase = cg * PITCHW + 2 * slot;

    // aff staging lane mapping (t < 208): dxl = t>>4, x-chunk xo4 = (t&15)*4.
    // LDS dest: wave-uniform base + lane*16B -> word t*4 = dxl*64 + xo4.
    const int dxl = t >> 4;
    const int xo4 = (t & 15) * 4;
    const float* gaff = aff + ((size_t)b * ND + dxl) * (NH * NW)
                            + (size_t)y * NW + X0 + xo4;       // dy = 0 slice
    unsigned* const affdst = affw + ((t >> 6) << 8);           // + sel*AFFW

    // ---- prologue: aff slice dy=0 -> affw[0]; window row y-6 -> ldsw[0] ----
    if (t < WIN * 16) gll16(gaff, affdst);
    gaff += (size_t)WIN * (NH * NW);
    {
        const int r0 = y - KD;
        if (r0 >= 0) {
            const float* p = in2_b + (size_t)r0 * NW;
            float4 Sv[5];
#pragma unroll
            for (int s = 0; s < 5; ++s)
                if (wadr[s] >= 0) Sv[s] = *(const float4*)&p[goff[s]];
#pragma unroll
            for (int s = 0; s < 5; ++s)
                if (wadr[s] >= 0) {
                    uint2 w; w.x = pk(Sv[s].x, Sv[s].y); w.y = pk(Sv[s].z, Sv[s].w);
                    *(uint2*)&ldsw[wadr[s]] = w;
                }
        }
    }
    __syncthreads();

    for (int rr = 0; rr < WIN; ++rr) {
        const unsigned* cur = ldsw + ((rr & 1) ? BUFW : 0);
        unsigned*       nxt = ldsw + ((rr & 1) ? 0 : BUFW);
        const unsigned* acur = affw + ((rr & 1) ? AFFW : 0) + slot * 4;
        const int  r  = y - KD + rr;
        const bool pv = (r >= 0) && (r < NH);          // block-uniform
        const int  rn = r + 1;
        const bool sv = (rr < WIN - 1) && (rn >= 0) && (rn < NH);

        // 1. async-stage aff slice dy=rr+1 into the other aff buffer (0 VGPR)
        if (rr < WIN - 1) {
            if (t < WIN * 16)
                gll16(gaff, affdst + ((rr & 1) ? 0 : AFFW));
            gaff += (size_t)WIN * (NH * NW);
        }
        // 2. issue in2 staging loads for row rn; pin so they can't sink
        float4 Sv[5];
        if (sv) {
            const float* p = in2_b + (size_t)rn * NW;
#pragma unroll
            for (int s = 0; s < 5; ++s)
                if (wadr[s] >= 0) Sv[s] = *(const float4*)&p[goff[s]];
#pragma unroll
            for (int s = 0; s < 5; ++s)
                asm volatile("" : "+v"(Sv[s].x), "+v"(Sv[s].y),
                                  "+v"(Sv[s].z), "+v"(Sv[s].w));
        }
        __builtin_amdgcn_sched_barrier(0);

        // 3. pass: window words once (W[4][10]), aff in 4-float4 chunks
        if (pv) {
            unsigned W[4][10];
#pragma unroll
            for (int i = 0; i < 4; ++i) {
                const unsigned* wp = cur + wbase + i * (16 * PITCHW);
                *(uint2*)&W[i][0] = *(const uint2*)&wp[0];
                *(uint2*)&W[i][2] = *(const uint2*)&wp[2];
                *(uint2*)&W[i][4] = *(const uint2*)&wp[4];
                *(uint2*)&W[i][6] = *(const uint2*)&wp[6];
                *(uint2*)&W[i][8] = *(const uint2*)&wp[8];
            }
#pragma unroll
            for (int m = 0; m < 3; ++m) {              // dx = 4m .. 4m+3
                alignas(16) float A[4][4];
                *(float4*)&A[0][0] = *(const float4*)&acur[(4*m+0)*64];
                *(float4*)&A[1][0] = *(const float4*)&acur[(4*m+1)*64];
                *(float4*)&A[2][0] = *(const float4*)&acur[(4*m+2)*64];
                *(float4*)&A[3][0] = *(const float4*)&acur[(4*m+3)*64];
#pragma unroll
                for (int i = 0; i < 4; ++i) {
#pragma unroll
                    for (int j = 0; j < 4; ++j) {
                        float a = acc[i][j];
                        a = fmaf(A[0][j], hget(W[i][(j+4*m+2)>>1], (j+4*m+2)&1), a);
                        a = fmaf(A[1][j], hget(W[i][(j+4*m+3)>>1], (j+4*m+3)&1), a);
                        a = fmaf(A[2][j], hget(W[i][(j+4*m+4)>>1], (j+4*m+4)&1), a);
                        a = fmaf(A[3][j], hget(W[i][(j+4*m+5)>>1], (j+4*m+5)&1), a);
                        acc[i][j] = a;
                    }
                }
            }
            {                                          // dx = 12 tail
                alignas(16) float At[4];
                *(float4*)&At[0] = *(const float4*)&acur[12 * 64];
#pragma unroll
                for (int i = 0; i < 4; ++i)
#pragma unroll
                    for (int j = 0; j < 4; ++j)
                        acc[i][j] = fmaf(At[j],
                            hget(W[i][(j+14)>>1], (j+14)&1), acc[i][j]);
            }
        }

        // 4. pack + write the staged in2 row into the other window buffer
        if (sv) {
#pragma unroll
            for (int s = 0; s < 5; ++s)
                if (wadr[s] >= 0) {
                    uint2 w; w.x = pk(Sv[s].x, Sv[s].y); w.y = pk(Sv[s].z, Sv[s].w);
                    *(uint2*)&nxt[wadr[s]] = w;
                }
        }

        __syncthreads();   // drains vmcnt (gll writes) + lgkm; flips buffers
    }

    float* ob = out + (((size_t)b * NC + cg) * NH + y) * NW + x0;
#pragma unroll
    for (int i = 0; i < 4; ++i) {
        *(float4*)&ob[(size_t)(16 * i) * NH * NW] =
            make_float4(acc[i][0], acc[i][1], acc[i][2], acc[i][3]);
    }
}

extern "C" void kernel_launch(void* const* d_in, const int* in_sizes, int n_in,
                              void* d_out, int out_size, void* d_ws, size_t ws_size,
                              hipStream_t stream) {
    const float* aff = (const float*)d_in[0];   // [4,169,192,192] f32
    const float* in2 = (const float*)d_in[1];   // [4, 64,192,192] f32
    float* outp = (float*)d_out;                // [4, 64,192,192] f32
    dim3 grid(NB * NH, 3, 1);                   // (xcd|b|y, xb)
    dim3 block(NTH);
    hipLaunchKernelGGL(mxassemble, grid, block, 0, stream, aff, in2, outp);
}

// Round 5
// 260.625 us; speedup vs baseline: 1.5534x; 1.0784x over previous
//
#include <hip/hip_runtime.h>

// out[b,c,y,x] = sum_{dy,dx in [0,13)} aff[b, dy*13+dx, y, x] * in2_zp[b, c, y+dy-6, x+dx-6]
// B=4 C=64 H=W=192 D=169.
//
// Round 11: r10 (161us, VALUBusy 44%, Occ 31%) left two coupled costs, both
// from keeping aff fp32 in LDS: a fat pass (13 ds_read_b128 + 208 fma_mix
// per iter) and a fat aff buffer (6.5KB dbuf) holding occupancy at 4 blocks
// (waves_per_eu max) / 5 (LDS). Fix both: stage aff as fp16 dx-PAIRS and
// dot2 the pass (r6-proven numerics, now without r6's reg-held aff):
//  * staging threads t<112 each load 2 float4 (rows dx=2m, 2m+1 of the next
//    dy-slice), cvt_pkrtz into 4 pair-words, ds_write_b128 to apk[m][xc*4].
//    Pinned with asm volatile (r10's proven anti-sink pattern); only 8 regs.
//  * pass: per m-chunk one b128 (4 pair-words, broadcast across cg lanes,
//    conflict-free) + per i: 2 v_alignbit (S words) + 4 v_dot2_f32_f16.
//    168 VALU/iter vs 208 fma_mix + fewer LDS reads (7 vs 13 b128).
//  * LDS 25088B (window 2x10752 + apk 2x1792) -> 6 blocks by LDS;
//    waves_per_eu(4,8) removes the old max-4 cap; liveness ~100 VGPR ->
//    5 waves/SIMD by regs. Occupancy cap 50%->62%.
//  * everything else (window layout, pitch 42, Sv staging, grid (768,3)
//    XCD swizzle, single barrier/iter) unchanged from r10.
// Numerics: aff fp16 rtz + in2 fp16 rtz, fp32 accum (= r6/r7, absmax .25-.5).

#define KD   6
#define WIN  13
#define ND   169
#define NB   4
#define NC   64
#define NH   192
#define NW   192
#define HW   (NH * NW)
#define XH   64            // x-tile width per block (3 tiles across W)
#define PITCHW 42          // window LDS row pitch in words (84 halves >= 80)
#define BUFW (NC * PITCHW) // 2688 words per window buffer
#define AFFPW 448          // 7*64 pair-words per packed aff slice
#define NTH  256           // 4 waves

typedef _Float16 half2v __attribute__((ext_vector_type(2)));

static __device__ __forceinline__ half2v h2(unsigned u) {
    return __builtin_bit_cast(half2v, u);
}
static __device__ __forceinline__ unsigned pk(float a, float b) {
    return __builtin_bit_cast(unsigned, __builtin_amdgcn_cvt_pkrtz(a, b));
}

#if __has_builtin(__builtin_amdgcn_fdot2)
#define FDOT2(a, b, c) __builtin_amdgcn_fdot2((a), (b), (c), false)
#else
static __device__ __forceinline__ float fdot2_fb(half2v a, half2v b, float c) {
    return fmaf((float)a.x, (float)b.x, fmaf((float)a.y, (float)b.y, c));
}
#define FDOT2(a, b, c) fdot2_fb((a), (b), (c))
#endif

__global__ __launch_bounds__(NTH)
__attribute__((amdgpu_waves_per_eu(4, 8)))
void mxassemble(const float* __restrict__ aff,
                const float* __restrict__ in2,
                float* __restrict__ out) {
    __shared__ unsigned ldsw[2 * BUFW];    // fp16 window rows, double buffered
    __shared__ unsigned apkw[2 * AFFPW];   // fp16 aff dx-pair slices, dbuf

    // Grid (768, 3): bx = (k<<3)|g. Per XCD g: k = b*24 + yl, yl fastest;
    // y = 24*g + yl -> each XCD owns a 24-row band per batch, rows L2-hot.
    const int bx = blockIdx.x;
    const int g  = bx & 7;
    const int k  = bx >> 3;                // 0..95
    const int b  = k / 24;
    const int yl = k - 24 * b;
    const int y  = 24 * g + yl;
    const int xb = blockIdx.y;             // x-tile 0..2
    const int X0 = xb * XH;

    const int t    = threadIdx.x;
    const int l    = t & 63;
    const int wv   = t >> 6;               // wave 0..3
    const int cg   = l & 15;               // channel group; c = cg + 16*i
    const int xs   = l >> 4;               // 0..3
    const int slot = wv * 4 + xs;          // 0..15
    const int x0   = X0 + slot * 4;

    // Window row layout: half j in [0,80) <-> global x = X0 - 8 + j.
    // Zero the 8-half OOB aprons once (xb=0: words 0..3; xb=2: words 36..39).
    if (xb != 1) {
        const int w0 = (xb == 0) ? 0 : 36;
        if (t < NC * 2) {
            const int c = t >> 1, qq = t & 1;
            *(uint2*)&ldsw[c * PITCHW + w0 + 2 * qq]        = make_uint2(0u, 0u);
            *(uint2*)&ldsw[BUFW + c * PITCHW + w0 + 2 * qq] = make_uint2(0u, 0u);
        }
    }

    // in2 staging slots: item s covers (c, q) = 4 floats; 64ch x 20 chunks
    // = 1280 = 256 threads x 5.
    int wadr[5], goff[5];
#pragma unroll
    for (int s = 0; s < 5; ++s) {
        const int ii = t + NTH * s;
        const int c  = ii / 20;
        const int q  = ii - 20 * c;
        const int xg = X0 - 8 + 4 * q;
        const bool ok = (xg >= 0) && (xg < NW);
        wadr[s] = ok ? (c * PITCHW + 2 * q) : -1;
        goff[s] = c * HW + xg;
    }

    // aff pair-staging mapping (t < 112): m = t>>4 in [0,7), xc = t&15.
    // Loads rows dx=2m (and 2m+1 when m<6) at x-chunk xc; writes pair-words
    // apk[m*64 + 4*xc .. +3] (b128).
    const int am  = t >> 4;
    const int axc = t & 15;
    const bool astg = (t < 112);
    const float* pA0 = aff + (size_t)b * ND * HW + (size_t)y * NW + X0
                           + 4 * axc + (size_t)(2 * am) * HW;
    const int aw = am * 64 + 4 * axc;

    float acc[4][4];
#pragma unroll
    for (int i = 0; i < 4; ++i)
#pragma unroll
        for (int j = 0; j < 4; ++j) acc[i][j] = 0.f;

    const float* in2_b = in2 + (size_t)b * NC * HW;
    const int wbase = cg * PITCHW + 2 * slot;

    // ---- prologue: packed aff slice dy=0 -> apkw[0]; row y-6 -> ldsw[0] ----
    if (astg) {
        const float4 A0 = *(const float4*)pA0;
        float4 A1 = make_float4(0.f, 0.f, 0.f, 0.f);
        if (am < 6) A1 = *(const float4*)(pA0 + HW);
        uint4 w;
        w.x = pk(A0.x, A1.x); w.y = pk(A0.y, A1.y);
        w.z = pk(A0.z, A1.z); w.w = pk(A0.w, A1.w);
        *(uint4*)&apkw[aw] = w;
    }
    {
        const int r0 = y - KD;
        if (r0 >= 0) {
            const float* p = in2_b + (size_t)r0 * NW;
            float4 Sv[5];
#pragma unroll
            for (int s = 0; s < 5; ++s)
                if (wadr[s] >= 0) Sv[s] = *(const float4*)&p[goff[s]];
#pragma unroll
            for (int s = 0; s < 5; ++s)
                if (wadr[s] >= 0) {
                    uint2 w; w.x = pk(Sv[s].x, Sv[s].y); w.y = pk(Sv[s].z, Sv[s].w);
                    *(uint2*)&ldsw[wadr[s]] = w;
                }
        }
    }
    __syncthreads();

    for (int rr = 0; rr < WIN; ++rr) {
        const unsigned* cur  = ldsw + ((rr & 1) ? BUFW : 0);
        unsigned*       nxt  = ldsw + ((rr & 1) ? 0 : BUFW);
        const unsigned* acur = apkw + ((rr & 1) ? AFFPW : 0) + 4 * slot;
        unsigned*       anxt = apkw + ((rr & 1) ? 0 : AFFPW);
        const int  r  = y - KD + rr;
        const bool pv = (r >= 0) && (r < NH);          // block-uniform
        const int  rn = r + 1;
        const bool sv = (rr < WIN - 1) && (rn >= 0) && (rn < NH);

        // 1. issue aff-pair loads for slice dy=rr+1; pin (anti-sink, r10)
        float4 A0, A1;
        const bool av = astg && (rr < WIN - 1);
        if (av) {
            const float* p = pA0 + (size_t)((rr + 1) * WIN) * HW;
            A0 = *(const float4*)p;
            A1 = make_float4(0.f, 0.f, 0.f, 0.f);
            if (am < 6) A1 = *(const float4*)(p + HW);
            asm volatile("" : "+v"(A0.x), "+v"(A0.y), "+v"(A0.z), "+v"(A0.w));
            asm volatile("" : "+v"(A1.x), "+v"(A1.y), "+v"(A1.z), "+v"(A1.w));
        }
        // 2. issue in2 staging loads for row rn; pin
        float4 Sv[5];
        if (sv) {
            const float* p = in2_b + (size_t)rn * NW;
#pragma unroll
            for (int s = 0; s < 5; ++s)
                if (wadr[s] >= 0) Sv[s] = *(const float4*)&p[goff[s]];
#pragma unroll
            for (int s = 0; s < 5; ++s)
                asm volatile("" : "+v"(Sv[s].x), "+v"(Sv[s].y),
                                  "+v"(Sv[s].z), "+v"(Sv[s].w));
        }
        __builtin_amdgcn_sched_barrier(0);

        // 3. pass: W words per i (P_k = W[i][k]), 7 m-chunks of dot2
        if (pv) {
            unsigned W[4][10];
#pragma unroll
            for (int i = 0; i < 4; ++i) {
                const unsigned* wp = cur + wbase + i * (16 * PITCHW);
                *(uint2*)&W[i][0] = *(const uint2*)&wp[0];
                *(uint2*)&W[i][2] = *(const uint2*)&wp[2];
                *(uint2*)&W[i][4] = *(const uint2*)&wp[4];
                *(uint2*)&W[i][6] = *(const uint2*)&wp[6];
                *(uint2*)&W[i][8] = *(const uint2*)&wp[8];
            }
#pragma unroll
            for (int m = 0; m < 7; ++m) {
                unsigned A4[4];
                *(uint4*)&A4[0] = *(const uint4*)&acur[m * 64];
#pragma unroll
                for (int i = 0; i < 4; ++i) {
                    const unsigned p1 = W[i][m + 1];
                    const unsigned p2 = W[i][m + 2];
                    const unsigned p3 = W[i][m + 3];
                    const unsigned s1 = (p1 >> 16) | (p2 << 16);
                    const unsigned s2 = (p2 >> 16) | (p3 << 16);
                    acc[i][0] = FDOT2(h2(A4[0]), h2(p1), acc[i][0]);
                    acc[i][1] = FDOT2(h2(A4[1]), h2(s1), acc[i][1]);
                    acc[i][2] = FDOT2(h2(A4[2]), h2(p2), acc[i][2]);
                    acc[i][3] = FDOT2(h2(A4[3]), h2(s2), acc[i][3]);
                }
            }
        }

        // 4. pack + write the staged aff pairs and in2 row (other buffers)
        if (av) {
            uint4 w;
            w.x = pk(A0.x, A1.x); w.y = pk(A0.y, A1.y);
            w.z = pk(A0.z, A1.z); w.w = pk(A0.w, A1.w);
            *(uint4*)&anxt[aw] = w;
        }
        if (sv) {
#pragma unroll
            for (int s = 0; s < 5; ++s)
                if (wadr[s] >= 0) {
                    uint2 w; w.x = pk(Sv[s].x, Sv[s].y); w.y = pk(Sv[s].z, Sv[s].w);
                    *(uint2*)&nxt[wadr[s]] = w;
                }
        }

        __syncthreads();   // drains staging (lgkm) + flips buffers
    }

    float* ob = out + (((size_t)b * NC + cg) * NH + y) * NW + x0;
#pragma unroll
    for (int i = 0; i < 4; ++i) {
        *(float4*)&ob[(size_t)(16 * i) * HW] =
            make_float4(acc[i][0], acc[i][1], acc[i][2], acc[i][3]);
    }
}

extern "C" void kernel_launch(void* const* d_in, const int* in_sizes, int n_in,
                              void* d_out, int out_size, void* d_ws, size_t ws_size,
                              hipStream_t stream) {
    const float* aff = (const float*)d_in[0];   // [4,169,192,192] f32
    const float* in2 = (const float*)d_in[1];   // [4, 64,192,192] f32
    float* outp = (float*)d_out;                // [4, 64,192,192] f32
    dim3 grid(NB * NH, 3, 1);                   // (xcd|b|y, xb)
    dim3 block(NTH);
    hipLaunchKernelGGL(mxassemble, grid, block, 0, stream, aff, in2, outp);
}